// Round 14
// baseline (267.491 us; speedup 1.0000x reference)
//
#include <hip/hip_runtime.h>
#include <stdint.h>

#define B_SZ   4096
#define OBS    512
#define T_TASKS 10
#define E_EXP  8
#define W_DIM  1024
#define H_OUT  12
#define XROW   522      // OBS + T
#define NTOT   8192     // E*W

using f32x4  = __attribute__((ext_vector_type(4))) float;
using bf16x8 = __attribute__((ext_vector_type(8))) short;

__device__ __forceinline__ unsigned short f2bf(float f) {
  union { float f; unsigned u; } x; x.f = f;
  unsigned r = x.u + 0x7FFF + ((x.u >> 16) & 1);   // RNE
  return (unsigned short)(r >> 16);
}
__device__ __forceinline__ float bf2f(unsigned short h) {
  union { unsigned u; float f; } x; x.u = ((unsigned)h) << 16;
  return x.f;
}

__device__ __forceinline__ void gload_lds16(const void* g, void* l) {
  __builtin_amdgcn_global_load_lds(
      (const __attribute__((address_space(1))) void*)g,
      (__attribute__((address_space(3))) void*)l,
      16, 0, 0);
}

#define VMCNT0  asm volatile("s_waitcnt vmcnt(0)" ::: "memory")
#define BARRIER asm volatile("s_barrier" ::: "memory")

// ---------------- prep kernels ----------------

__global__ void k_obs_bf16(const float* __restrict__ x, unsigned short* __restrict__ obsB) {
  int i = blockIdx.x * 256 + threadIdx.x;          // over B*OBS, exact grid
  int b = i >> 9, c = i & 511;
  obsB[i] = f2bf(x[(size_t)b * XROW + c]);
}

// W [e][K][1024] f32  ->  Wt [e][1024][K] bf16. 64x64 tiles, vectorized both sides.
__global__ void k_wt64(const float* __restrict__ Wsrc, unsigned short* __restrict__ Wt, int K) {
  __shared__ float tile[64][65];
  int e  = blockIdx.z;
  int n0 = blockIdx.x * 64, k0 = blockIdx.y * 64;
  const float* Ws = Wsrc + (size_t)e * K * W_DIM;
  unsigned short* Wd = Wt + (size_t)e * W_DIM * K;
  int tid = threadIdx.x;
  int tx = tid & 15, ty = tid >> 4;                // tx: n-float4 idx, ty: 0..15
#pragma unroll
  for (int r = 0; r < 4; ++r) {
    int k = ty + r * 16;
    float4 v = *(const float4*)&Ws[(size_t)(k0 + k) * W_DIM + n0 + tx * 4];
    tile[k][tx * 4 + 0] = v.x; tile[k][tx * 4 + 1] = v.y;
    tile[k][tx * 4 + 2] = v.z; tile[k][tx * 4 + 3] = v.w;
  }
  __syncthreads();
  int n = tid >> 2, kc = (tid & 3) * 16;
  bf16x8 o0, o1;
#pragma unroll
  for (int j = 0; j < 8; ++j) o0[j] = (short)f2bf(tile[kc + j][n]);
#pragma unroll
  for (int j = 0; j < 8; ++j) o1[j] = (short)f2bf(tile[kc + 8 + j][n]);
  unsigned short* dst = &Wd[(size_t)(n0 + n) * K + k0 + kc];
  *(bf16x8*)&dst[0] = o0;
  *(bf16x8*)&dst[8] = o1;
}

// ---------------- 256x128 GEMM, BK=32, 48KB LDS dbuf -> 3 blocks/CU ----------------
// 512 thr = 8 waves (4M x 2N), per-wave output 64x64 -> acc[4][4]=64 VGPR (compiles
// to 56 total, measured r12 — no spill). Buffer = A 16KB + B 8KB = 24576 B; dbuf
// 49152 B/block -> floor(160/48) = 3 blocks/CU = 24 waves/CU. (r12 measured this
// geometry at 1 block/CU due to a 2x stride bug — this run actually pulls the lever.)
// Window t: { stage(t+1)->nbuf (3 gload_lds16) ; 8 ds_read_b128 ; 16 MFMA ;
//             vmcnt(0) ; barrier }  — 3 independent blocks/CU hide each other's
// drain+barrier idle (m114). Swizzle: chunk p = kg ^ ((r>>1)&3); per-wave read
// covers each bank exactly 2x (free, m136); 0 conflicts measured r10-r12.

template <bool RELU>
__global__ __launch_bounds__(512, 4) void k_gemm256(
    const unsigned short* __restrict__ A, int lda, int aExpStride,
    const unsigned short* __restrict__ Bt, int K,
    const float* __restrict__ bias,
    unsigned short* __restrict__ C)
{
  extern __shared__ char lds[];
  const int tid  = threadIdx.x;
  const int lane = tid & 63, wid = tid >> 6;
  const int wm = wid >> 1, wn = wid & 1;           // 4M x 2N waves
  const int rlo = lane & 15, kg = lane >> 4;       // kg 0..3 = 16B chunk

  // bijective XCD swizzle: 1024 blocks -> 8 XCDs (2x4 supergrid), 8m x 16n each
  int bid = blockIdx.x;
  int xcd = bid & 7, loc = bid >> 3;               // loc 0..127
  int mblk = (xcd & 1) * 8 + (loc & 7);            // 0..15
  int nblk = (xcd >> 1) * 16 + (loc >> 3);         // 0..63
  int m0 = mblk * 256, n0g = nblk * 128;
  int e = n0g >> 10, n0e = n0g & 1023;

  const unsigned short* Ab = A + (size_t)e * aExpStride;
  const unsigned short* Bb = Bt + ((size_t)e * 1024 + n0e) * (size_t)K;

  // staging: A 256 rows x 4 chunks = 1024 chunks (2/thread); B 128 x 4 = 512 (1/thread)
  const int idx0 = tid, idx1 = 512 + tid;
  const int r0 = idx0 >> 2, c0 = (idx0 & 3) ^ ((r0 >> 1) & 3);  // inverse-swz source
  const int r1 = idx1 >> 2, c1 = (idx1 & 3) ^ ((r1 >> 1) & 3);

  const int NT = K >> 5;
  const size_t ldaz = (size_t)lda, ldkz = (size_t)K;

  auto stage = [&](int buf, int kt) {
    const unsigned short* gA = Ab + kt * 32;
    const unsigned short* gB = Bb + kt * 32;
    char* lA = lds + buf * 24576;                  // A = 256*64B = 16KB
    char* lB = lA + 16384;                         // B = 128*64B = 8KB
    gload_lds16(gA + (size_t)(m0 + r0) * ldaz + c0 * 8, lA + idx0 * 16);
    gload_lds16(gA + (size_t)(m0 + r1) * ldaz + c1 * 8, lA + idx1 * 16);
    gload_lds16(gB + (size_t)r0 * ldkz + c0 * 8, lB + idx0 * 16);
  };
  auto rdA = [&](int buf, int mi) -> bf16x8 {
    int r = wm * 64 + mi * 16 + rlo;
    int p = kg ^ ((r >> 1) & 3);
    return *(const bf16x8*)(lds + buf * 24576 + r * 64 + p * 16);
  };
  auto rdB = [&](int buf, int ni) -> bf16x8 {
    int r = wn * 64 + ni * 16 + rlo;
    int p = kg ^ ((r >> 1) & 3);
    return *(const bf16x8*)(lds + buf * 24576 + 16384 + r * 64 + p * 16);
  };

  f32x4 acc[4][4];
#pragma unroll
  for (int i = 0; i < 4; ++i)
#pragma unroll
    for (int j = 0; j < 4; ++j) acc[i][j] = f32x4{0.f, 0.f, 0.f, 0.f};

  // prologue: tile 0 into buf 0
  stage(0, 0);
  VMCNT0;
  BARRIER;

  for (int t = 0; t < NT; ++t) {
    int buf = t & 1;
    int tn = (t + 1 < NT) ? t + 1 : NT - 1;        // tail: dead data into unread buf

    stage(buf ^ 1, tn);                            // issue next tile first (latency)

    bf16x8 af[4], bf[4];
#pragma unroll
    for (int mi = 0; mi < 4; ++mi) af[mi] = rdA(buf, mi);
#pragma unroll
    for (int ni = 0; ni < 4; ++ni) bf[ni] = rdB(buf, ni);

    __builtin_amdgcn_s_setprio(1);
#pragma unroll
    for (int mi = 0; mi < 4; ++mi)
#pragma unroll
      for (int ni = 0; ni < 4; ++ni)
        acc[mi][ni] = __builtin_amdgcn_mfma_f32_16x16x32_bf16(af[mi], bf[ni], acc[mi][ni], 0, 0, 0);
    __builtin_amdgcn_s_setprio(0);

    VMCNT0;                                        // stage(t+1) landed (full-window distance)
    BARRIER;                                       // buf(t+1) globally established
  }

  // epilogue: bias (+ReLU) + bf16 store
  int rbase = kg * 4;
#pragma unroll
  for (int mi = 0; mi < 4; ++mi) {
    int rowg = m0 + wm * 64 + mi * 16 + rbase;
#pragma unroll
    for (int ni = 0; ni < 4; ++ni) {
      int colr = wn * 64 + ni * 16 + rlo;
      int colg = n0g + colr;
      float bv = bias[e * W_DIM + n0e + colr];
#pragma unroll
      for (int j = 0; j < 4; ++j) {
        float v = acc[mi][ni][j] + bv;
        if (RELU) v = fmaxf(v, 0.0f);
        C[(size_t)(rowg + j) * NTOT + colg] = f2bf(v);
      }
    }
  }
}

// ---------------- Gram-Schmidt + feat + head: one WAVE per batch row ----------------

__device__ __forceinline__ float wred(float s) {
#pragma unroll
  for (int m = 32; m; m >>= 1) s += __shfl_xor(s, m, 64);
  return s;
}

__global__ __launch_bounds__(256, 1) void k_gs_wave(
    const unsigned short* __restrict__ eo,   // [B][8192] bf16
    const float* __restrict__ x,
    const float* __restrict__ te_W,          // [10][8]
    const float* __restrict__ head_W,        // [10][1024][12]
    const float* __restrict__ head_b,        // [10][12]
    float* __restrict__ out)                 // [B][12]
{
  int wid = threadIdx.x >> 6, lane = threadIdx.x & 63;
  int b = blockIdx.x * 4 + wid;

  float v[8][16];
  const unsigned short* row = eo + (size_t)b * NTOT;
#pragma unroll
  for (int i = 0; i < E_EXP; ++i) {
#pragma unroll
    for (int half = 0; half < 2; ++half) {
      bf16x8 t = *(const bf16x8*)&row[i * 1024 + half * 512 + lane * 8];
#pragma unroll
      for (int k = 0; k < 8; ++k) v[i][half * 8 + k] = bf2f((unsigned short)t[k]);
    }
  }

  int idx = 0; float mv = x[(size_t)b * XROW + OBS];
#pragma unroll
  for (int t = 1; t < T_TASKS; ++t) {
    float val = x[(size_t)b * XROW + OBS + t];
    if (val > mv) { mv = val; idx = t; }
  }

  float cf[7];
#pragma unroll
  for (int i = 0; i < E_EXP; ++i) {
#pragma unroll
    for (int j = 0; j < 7; ++j) {
      if (j < i) {
        float p = 0.f;
#pragma unroll
        for (int c = 0; c < 16; ++c) p += v[i][c] * v[j][c];
        cf[j] = wred(p);
      }
    }
#pragma unroll
    for (int c = 0; c < 16; ++c) {
      float w = v[i][c];
#pragma unroll
      for (int j = 0; j < 7; ++j)
        if (j < i) w -= cf[j] * v[j][c];
      v[i][c] = w;
    }
    float p = 0.f;
#pragma unroll
    for (int c = 0; c < 16; ++c) p += v[i][c] * v[i][c];
    float nrm = sqrtf(wred(p));
    float s = 1.0f / (nrm + 1e-8f);
#pragma unroll
    for (int c = 0; c < 16; ++c) v[i][c] *= s;
  }

  float te[E_EXP];
#pragma unroll
  for (int e2 = 0; e2 < E_EXP; ++e2) te[e2] = te_W[idx * E_EXP + e2];

  float ph[H_OUT];
#pragma unroll
  for (int h = 0; h < H_OUT; ++h) ph[h] = 0.f;
  const float* hw = head_W + (size_t)idx * W_DIM * H_OUT;

#pragma unroll
  for (int half = 0; half < 2; ++half) {
#pragma unroll
    for (int k = 0; k < 8; ++k) {
      int c = half * 512 + lane * 8 + k;
      float f = 0.f;
#pragma unroll
      for (int e2 = 0; e2 < E_EXP; ++e2) f += te[e2] * v[e2][half * 8 + k];
      // fast tanh: 1 - 2/(e^{2f}+1) via v_exp_f32
      float ex = __expf(2.0f * f);
      f = 1.0f - 2.0f / (ex + 1.0f);
      const float4* hw4 = (const float4*)(hw + (size_t)c * H_OUT);
      float4 h0 = hw4[0], h1 = hw4[1], h2 = hw4[2];
      ph[0] += f * h0.x;  ph[1] += f * h0.y;  ph[2]  += f * h0.z;  ph[3]  += f * h0.w;
      ph[4] += f * h1.x;  ph[5] += f * h1.y;  ph[6]  += f * h1.z;  ph[7]  += f * h1.w;
      ph[8] += f * h2.x;  ph[9] += f * h2.y;  ph[10] += f * h2.z;  ph[11] += f * h2.w;
    }
  }

#pragma unroll
  for (int h = 0; h < H_OUT; ++h) ph[h] = wred(ph[h]);
  if (lane == 0) {
#pragma unroll
    for (int h = 0; h < H_OUT; ++h)
      out[(size_t)b * H_OUT + h] = ph[h] + head_b[idx * H_OUT + h];
  }
}

// ---------------- launch ----------------

extern "C" void kernel_launch(void* const* d_in, const int* in_sizes, int n_in,
                              void* d_out, int out_size, void* d_ws, size_t ws_size,
                              hipStream_t stream) {
  const float* x     = (const float*)d_in[0];
  const float* te_W  = (const float*)d_in[1];
  const float* W0    = (const float*)d_in[2];
  const float* b0    = (const float*)d_in[3];
  const float* W1    = (const float*)d_in[4];
  const float* b1    = (const float*)d_in[5];
  const float* W2    = (const float*)d_in[6];
  const float* b2    = (const float*)d_in[7];
  const float* headW = (const float*)d_in[8];
  const float* headb = (const float*)d_in[9];
  float* out = (float*)d_out;

  char* ws = (char*)d_ws;
  size_t off = 0;
  auto alloc = [&](size_t bytes) {
    void* p = ws + off;
    off += (bytes + 255) & ~(size_t)255;
    return p;
  };
  unsigned short* obsB = (unsigned short*)alloc((size_t)B_SZ * OBS * 2);
  unsigned short* W0t  = (unsigned short*)alloc((size_t)8 * 1024 * 512 * 2);
  unsigned short* W1t  = (unsigned short*)alloc((size_t)8 * 1024 * 1024 * 2);
  unsigned short* W2t  = (unsigned short*)alloc((size_t)8 * 1024 * 1024 * 2);
  unsigned short* h0   = (unsigned short*)alloc((size_t)B_SZ * NTOT * 2);
  unsigned short* h1   = (unsigned short*)alloc((size_t)B_SZ * NTOT * 2);
  unsigned short* eo   = (unsigned short*)alloc((size_t)B_SZ * NTOT * 2);
  (void)ws_size; (void)in_sizes; (void)n_in; (void)out_size;

  k_obs_bf16<<<(B_SZ * OBS) / 256, 256, 0, stream>>>(x, obsB);
  k_wt64<<<dim3(16, 8, 8),  256, 0, stream>>>(W0, W0t, 512);
  k_wt64<<<dim3(16, 16, 8), 256, 0, stream>>>(W1, W1t, 1024);
  k_wt64<<<dim3(16, 16, 8), 256, 0, stream>>>(W2, W2t, 1024);

  k_gemm256<true ><<<1024, 512, 49152, stream>>>(obsB, 512,  0,    W0t, 512,  b0, h0);
  k_gemm256<true ><<<1024, 512, 49152, stream>>>(h0,   NTOT, 1024, W1t, 1024, b1, h1);
  k_gemm256<false><<<1024, 512, 49152, stream>>>(h1,   NTOT, 1024, W2t, 1024, b2, eo);

  k_gs_wave<<<B_SZ / 4, 256, 0, stream>>>(eo, x, te_W, headW, headb, out);
}

// Round 15
// 252.791 us; speedup vs baseline: 1.0582x; 1.0582x over previous
//
#include <hip/hip_runtime.h>
#include <stdint.h>

#define B_SZ   4096
#define OBS    512
#define T_TASKS 10
#define E_EXP  8
#define W_DIM  1024
#define H_OUT  12
#define XROW   522      // OBS + T
#define NTOT   8192     // E*W

using f32x4  = __attribute__((ext_vector_type(4))) float;
using f32x16 = __attribute__((ext_vector_type(16))) float;
using bf16x8 = __attribute__((ext_vector_type(8))) short;

__device__ __forceinline__ unsigned short f2bf(float f) {
  union { float f; unsigned u; } x; x.f = f;
  unsigned r = x.u + 0x7FFF + ((x.u >> 16) & 1);   // RNE
  return (unsigned short)(r >> 16);
}
__device__ __forceinline__ float bf2f(unsigned short h) {
  union { unsigned u; float f; } x; x.u = ((unsigned)h) << 16;
  return x.f;
}

__device__ __forceinline__ void gload_lds16(const void* g, void* l) {
  __builtin_amdgcn_global_load_lds(
      (const __attribute__((address_space(1))) void*)g,
      (__attribute__((address_space(3))) void*)l,
      16, 0, 0);
}

#define SCHED0  __builtin_amdgcn_sched_barrier(0)
#define VMCNT6  do { asm volatile("s_waitcnt vmcnt(6)" ::: "memory"); SCHED0; } while (0)
#define LGKM0   do { asm volatile("s_waitcnt lgkmcnt(0)" ::: "memory"); SCHED0; } while (0)
#define BARRIER do { SCHED0; asm volatile("s_barrier" ::: "memory"); SCHED0; } while (0)

// ---------------- prep kernels ----------------

__global__ void k_obs_bf16(const float* __restrict__ x, unsigned short* __restrict__ obsB) {
  int i = blockIdx.x * 256 + threadIdx.x;          // over B*OBS, exact grid
  int b = i >> 9, c = i & 511;
  obsB[i] = f2bf(x[(size_t)b * XROW + c]);
}

// W [e][K][1024] f32  ->  Wt [e][1024][K] bf16. 64x64 tiles, vectorized both sides.
__global__ void k_wt64(const float* __restrict__ Wsrc, unsigned short* __restrict__ Wt, int K) {
  __shared__ float tile[64][65];
  int e  = blockIdx.z;
  int n0 = blockIdx.x * 64, k0 = blockIdx.y * 64;
  const float* Ws = Wsrc + (size_t)e * K * W_DIM;
  unsigned short* Wd = Wt + (size_t)e * W_DIM * K;
  int tid = threadIdx.x;
  int tx = tid & 15, ty = tid >> 4;                // tx: n-float4 idx, ty: 0..15
#pragma unroll
  for (int r = 0; r < 4; ++r) {
    int k = ty + r * 16;
    float4 v = *(const float4*)&Ws[(size_t)(k0 + k) * W_DIM + n0 + tx * 4];
    tile[k][tx * 4 + 0] = v.x; tile[k][tx * 4 + 1] = v.y;
    tile[k][tx * 4 + 2] = v.z; tile[k][tx * 4 + 3] = v.w;
  }
  __syncthreads();
  int n = tid >> 2, kc = (tid & 3) * 16;
  bf16x8 o0, o1;
#pragma unroll
  for (int j = 0; j < 8; ++j) o0[j] = (short)f2bf(tile[kc + j][n]);
#pragma unroll
  for (int j = 0; j < 8; ++j) o1[j] = (short)f2bf(tile[kc + 8 + j][n]);
  unsigned short* dst = &Wd[(size_t)(n0 + n) * K + k0 + kc];
  *(bf16x8*)&dst[0] = o0;
  *(bf16x8*)&dst[8] = o1;
}

// ---------------- 256x256 GEMM, r13 schedule, 32x32x16 MFMA ----------------
// 512 thr = 8 waves (2M x 4N). BK=64, dbuf LDS 128 KB. Staging identical to r13.
// Per wave: 4 m-frags of 32 rows (2 halves x mi in {0,1}), 1 n-frag of 32 cols per
// B-half; acc = [hm][mi][hn] x f32x16 = 128 VGPR. 8 MFMA(32x32x16)/window = same
// FLOP as r13's 16 MFMA(16x16x32), at the 2382-2495 TF pipe (vs 2075-2176).
// A/B lane mapping (by analogy with verified 16x16x32): row/col = lane&31,
// k = (lane>>5)*8 + j. C/D: col = lane&31, row = (reg&3)+8*(reg>>2)+4*(lane>>5)
// [HW-verified m74/m101]. Read bank profile: p = (ks*2+(lane>>5)) ^ (r&7) spans
// 8 positions x 8 lanes each — identical aggregate pressure to r13's 0-conflict read.
// Stage map (m201): Q0 A1(t+1)->nbuf; Q1 A0(t+2)->buf; Q2 B0(t+2)->buf; Q3 B1(t+2)->buf;
// single vmcnt(6)@Q3 retires all of tile t+1 (FIFO proof as r13).

template <bool RELU>
__global__ __launch_bounds__(512, 2) void k_gemm256(
    const unsigned short* __restrict__ A, int lda, int aExpStride,
    const unsigned short* __restrict__ Bt, int K,
    const float* __restrict__ bias,
    unsigned short* __restrict__ C)
{
  extern __shared__ char lds[];
  const int tid  = threadIdx.x;
  const int lane = tid & 63, wid = tid >> 6;
  const int wm = wid >> 2, wn = wid & 3;
  const int l31 = lane & 31, lhi = lane >> 5;

  // bijective XCD swizzle: 512 blocks -> 8 XCDs x (8 mblk x 8 nblk)
  int bid = blockIdx.x;
  int xcd = bid & 7, loc = bid >> 3;
  int mblk = ((xcd & 1) << 3) | (loc & 7);
  int nblk = ((xcd >> 1) << 3) | (loc >> 3);
  int m0 = mblk * 256, n0g = nblk * 256;
  int e = n0g >> 10, n0e = n0g & 1023;

  const unsigned short* Ab = A + (size_t)e * aExpStride;
  const unsigned short* Bb = Bt + ((size_t)e * 1024 + n0e) * (size_t)K;

  // staging coords: half-tile = 128 rows x 8 chunks(16B) = 1024 chunks; 2/thread
  const int idx0 = tid, idx1 = 512 + tid;
  const int r0 = idx0 >> 3, p0 = idx0 & 7, c0 = p0 ^ (r0 & 7);  // inverse-swz source
  const int r1 = idx1 >> 3, p1 = idx1 & 7, c1 = p1 ^ (r1 & 7);

  const int NT = K >> 6;
  const size_t ldaz = (size_t)lda, ldkz = (size_t)K;

  auto stageA = [&](int buf, int h, int kt) {
    const unsigned short* g0 = Ab + (size_t)(m0 + h * 128 + r0) * ldaz + kt * 64 + c0 * 8;
    const unsigned short* g1 = Ab + (size_t)(m0 + h * 128 + r1) * ldaz + kt * 64 + c1 * 8;
    char* l = lds + buf * 65536 + h * 16384;
    gload_lds16(g0, l + idx0 * 16);
    gload_lds16(g1, l + idx1 * 16);
  };
  auto stageB = [&](int buf, int h, int kt) {
    const unsigned short* g0 = Bb + (size_t)(h * 128 + r0) * ldkz + kt * 64 + c0 * 8;
    const unsigned short* g1 = Bb + (size_t)(h * 128 + r1) * ldkz + kt * 64 + c1 * 8;
    char* l = lds + buf * 65536 + 32768 + h * 16384;
    gload_lds16(g0, l + idx0 * 16);
    gload_lds16(g1, l + idx1 * 16);
  };
  // 32-row A fragment: rows mi*64 + wm*32 + l31 of half mh; k-chunk = ks*2 + lhi
  auto rdA = [&](int buf, int mh, int mi, int ks) -> bf16x8 {
    int r = mi * 64 + wm * 32 + l31;
    int p = (ks * 2 + lhi) ^ (r & 7);              // swizzled read
    return *(const bf16x8*)(lds + buf * 65536 + mh * 16384 + r * 128 + p * 16);
  };
  // 32-col B fragment: cols wn*32 + l31 of half nh
  auto rdB = [&](int buf, int nh, int ks) -> bf16x8 {
    int r = wn * 32 + l31;
    int p = (ks * 2 + lhi) ^ (r & 7);
    return *(const bf16x8*)(lds + buf * 65536 + 32768 + nh * 16384 + r * 128 + p * 16);
  };

  f32x16 acc[2][2][2];                             // [hm][mi][hn], 128 VGPR
#pragma unroll
  for (int i = 0; i < 2; ++i)
#pragma unroll
    for (int j = 0; j < 2; ++j)
#pragma unroll
      for (int k = 0; k < 2; ++k)
#pragma unroll
        for (int q = 0; q < 16; ++q) acc[i][j][k][q] = 0.f;

  bf16x8 af[8], bf0[4], bf1[4];                    // af[mi*4+ks]

  // prologue: tile0 (A0,B0,B1,A1) + tile1 (A0,B0,B1) = 14 loads; vmcnt(6) retires tile0.
  {
    int t1 = NT > 1 ? 1 : 0;
    stageA(0, 0, 0); stageB(0, 0, 0); stageB(0, 1, 0); stageA(0, 1, 0);
    stageA(1, 0, t1); stageB(1, 0, t1); stageB(1, 1, t1);
    VMCNT6;
    BARRIER;
  }

  for (int t = 0; t < NT; ++t) {
    int buf = t & 1, nbuf = buf ^ 1;
    int tn  = (t + 1 < NT) ? t + 1 : NT - 1;       // clamped: counts stay exact;
    int tn2 = (t + 2 < NT) ? t + 2 : NT - 1;       // dead data lands in unread slots

    // ---- Q0: reads af<-A0(t)[8], bf0<-B0(t)[4]; stage A1(t+1)->nbuf ----
#pragma unroll
    for (int mi = 0; mi < 2; ++mi)
#pragma unroll
      for (int ks = 0; ks < 4; ++ks) af[mi * 4 + ks] = rdA(buf, 0, mi, ks);
#pragma unroll
    for (int ks = 0; ks < 4; ++ks) bf0[ks] = rdB(buf, 0, ks);
    stageA(nbuf, 1, tn);
    BARRIER;
    LGKM0;
    __builtin_amdgcn_s_setprio(1);
#pragma unroll
    for (int ks = 0; ks < 4; ++ks)
#pragma unroll
      for (int mi = 0; mi < 2; ++mi)
        acc[0][mi][0] = __builtin_amdgcn_mfma_f32_32x32x16_bf16(af[mi * 4 + ks], bf0[ks], acc[0][mi][0], 0, 0, 0);
    __builtin_amdgcn_s_setprio(0);

    // ---- Q1: reads bf1<-B1(t)[4]; stage A0(t+2)->buf ----
#pragma unroll
    for (int ks = 0; ks < 4; ++ks) bf1[ks] = rdB(buf, 1, ks);
    stageA(buf, 0, tn2);
    BARRIER;
    LGKM0;
    __builtin_amdgcn_s_setprio(1);
#pragma unroll
    for (int ks = 0; ks < 4; ++ks)
#pragma unroll
      for (int mi = 0; mi < 2; ++mi)
        acc[0][mi][1] = __builtin_amdgcn_mfma_f32_32x32x16_bf16(af[mi * 4 + ks], bf1[ks], acc[0][mi][1], 0, 0, 0);
    __builtin_amdgcn_s_setprio(0);

    // ---- Q2: reads af<-A1(t)[8]; stage B0(t+2)->buf ----
#pragma unroll
    for (int mi = 0; mi < 2; ++mi)
#pragma unroll
      for (int ks = 0; ks < 4; ++ks) af[mi * 4 + ks] = rdA(buf, 1, mi, ks);
    stageB(buf, 0, tn2);
    BARRIER;
    LGKM0;
    __builtin_amdgcn_s_setprio(1);
#pragma unroll
    for (int ks = 0; ks < 4; ++ks)
#pragma unroll
      for (int mi = 0; mi < 2; ++mi)
        acc[1][mi][1] = __builtin_amdgcn_mfma_f32_32x32x16_bf16(af[mi * 4 + ks], bf1[ks], acc[1][mi][1], 0, 0, 0);
    __builtin_amdgcn_s_setprio(0);

    // ---- Q3: stage B1(t+2)->buf; vmcnt(6) retires all of tile t+1; no new reads ----
    stageB(buf, 1, tn2);
    VMCNT6;
    BARRIER;
    __builtin_amdgcn_s_setprio(1);
#pragma unroll
    for (int ks = 0; ks < 4; ++ks)
#pragma unroll
      for (int mi = 0; mi < 2; ++mi)
        acc[1][mi][0] = __builtin_amdgcn_mfma_f32_32x32x16_bf16(af[mi * 4 + ks], bf0[ks], acc[1][mi][0], 0, 0, 0);
    __builtin_amdgcn_s_setprio(0);
  }
  asm volatile("s_waitcnt vmcnt(0)" ::: "memory");
  SCHED0;

  // epilogue: bias (+ReLU) + bf16 store.
  // C/D map: col = l31, row = (j&3) + 8*(j>>2) + 4*lhi  [m74/m101]
#pragma unroll
  for (int hm = 0; hm < 2; ++hm)
#pragma unroll
    for (int mi = 0; mi < 2; ++mi)
#pragma unroll
      for (int hn = 0; hn < 2; ++hn) {
        int rowbase = m0 + hm * 128 + mi * 64 + wm * 32 + 4 * lhi;
        int colr = hn * 128 + wn * 32 + l31;
        int colg = n0g + colr;
        float bv = bias[e * W_DIM + n0e + colr];
#pragma unroll
        for (int j = 0; j < 16; ++j) {
          int row = rowbase + (j & 3) + 8 * (j >> 2);
          float v = acc[hm][mi][hn][j] + bv;
          if (RELU) v = fmaxf(v, 0.0f);
          C[(size_t)row * NTOT + colg] = f2bf(v);
        }
      }
}

// ---------------- Gram-Schmidt + feat + head: one WAVE per batch row ----------------

__device__ __forceinline__ float wred(float s) {
#pragma unroll
  for (int m = 32; m; m >>= 1) s += __shfl_xor(s, m, 64);
  return s;
}

__global__ __launch_bounds__(256, 1) void k_gs_wave(
    const unsigned short* __restrict__ eo,   // [B][8192] bf16
    const float* __restrict__ x,
    const float* __restrict__ te_W,          // [10][8]
    const float* __restrict__ head_W,        // [10][1024][12]
    const float* __restrict__ head_b,        // [10][12]
    float* __restrict__ out)                 // [B][12]
{
  int wid = threadIdx.x >> 6, lane = threadIdx.x & 63;
  int b = blockIdx.x * 4 + wid;

  float v[8][16];
  const unsigned short* row = eo + (size_t)b * NTOT;
#pragma unroll
  for (int i = 0; i < E_EXP; ++i) {
#pragma unroll
    for (int half = 0; half < 2; ++half) {
      bf16x8 t = *(const bf16x8*)&row[i * 1024 + half * 512 + lane * 8];
#pragma unroll
      for (int k = 0; k < 8; ++k) v[i][half * 8 + k] = bf2f((unsigned short)t[k]);
    }
  }

  int idx = 0; float mv = x[(size_t)b * XROW + OBS];
#pragma unroll
  for (int t = 1; t < T_TASKS; ++t) {
    float val = x[(size_t)b * XROW + OBS + t];
    if (val > mv) { mv = val; idx = t; }
  }

  float cf[7];
#pragma unroll
  for (int i = 0; i < E_EXP; ++i) {
#pragma unroll
    for (int j = 0; j < 7; ++j) {
      if (j < i) {
        float p = 0.f;
#pragma unroll
        for (int c = 0; c < 16; ++c) p += v[i][c] * v[j][c];
        cf[j] = wred(p);
      }
    }
#pragma unroll
    for (int c = 0; c < 16; ++c) {
      float w = v[i][c];
#pragma unroll
      for (int j = 0; j < 7; ++j)
        if (j < i) w -= cf[j] * v[j][c];
      v[i][c] = w;
    }
    float p = 0.f;
#pragma unroll
    for (int c = 0; c < 16; ++c) p += v[i][c] * v[i][c];
    float nrm = sqrtf(wred(p));
    float s = 1.0f / (nrm + 1e-8f);
#pragma unroll
    for (int c = 0; c < 16; ++c) v[i][c] *= s;
  }

  float te[E_EXP];
#pragma unroll
  for (int e2 = 0; e2 < E_EXP; ++e2) te[e2] = te_W[idx * E_EXP + e2];

  float ph[H_OUT];
#pragma unroll
  for (int h = 0; h < H_OUT; ++h) ph[h] = 0.f;
  const float* hw = head_W + (size_t)idx * W_DIM * H_OUT;

#pragma unroll
  for (int half = 0; half < 2; ++half) {
#pragma unroll
    for (int k = 0; k < 8; ++k) {
      int c = half * 512 + lane * 8 + k;
      float f = 0.f;
#pragma unroll
      for (int e2 = 0; e2 < E_EXP; ++e2) f += te[e2] * v[e2][half * 8 + k];
      // fast tanh: 1 - 2/(e^{2f}+1) via v_exp_f32
      float ex = __expf(2.0f * f);
      f = 1.0f - 2.0f / (ex + 1.0f);
      const float4* hw4 = (const float4*)(hw + (size_t)c * H_OUT);
      float4 h0 = hw4[0], h1 = hw4[1], h2 = hw4[2];
      ph[0] += f * h0.x;  ph[1] += f * h0.y;  ph[2]  += f * h0.z;  ph[3]  += f * h0.w;
      ph[4] += f * h1.x;  ph[5] += f * h1.y;  ph[6]  += f * h1.z;  ph[7]  += f * h1.w;
      ph[8] += f * h2.x;  ph[9] += f * h2.y;  ph[10] += f * h2.z;  ph[11] += f * h2.w;
    }
  }

#pragma unroll
  for (int h = 0; h < H_OUT; ++h) ph[h] = wred(ph[h]);
  if (lane == 0) {
#pragma unroll
    for (int h = 0; h < H_OUT; ++h)
      out[(size_t)b * H_OUT + h] = ph[h] + head_b[idx * H_OUT + h];
  }
}

// ---------------- launch ----------------

extern "C" void kernel_launch(void* const* d_in, const int* in_sizes, int n_in,
                              void* d_out, int out_size, void* d_ws, size_t ws_size,
                              hipStream_t stream) {
  const float* x     = (const float*)d_in[0];
  const float* te_W  = (const float*)d_in[1];
  const float* W0    = (const float*)d_in[2];
  const float* b0    = (const float*)d_in[3];
  const float* W1    = (const float*)d_in[4];
  const float* b1    = (const float*)d_in[5];
  const float* W2    = (const float*)d_in[6];
  const float* b2    = (const float*)d_in[7];
  const float* headW = (const float*)d_in[8];
  const float* headb = (const float*)d_in[9];
  float* out = (float*)d_out;

  char* ws = (char*)d_ws;
  size_t off = 0;
  auto alloc = [&](size_t bytes) {
    void* p = ws + off;
    off += (bytes + 255) & ~(size_t)255;
    return p;
  };
  unsigned short* obsB = (unsigned short*)alloc((size_t)B_SZ * OBS * 2);
  unsigned short* W0t  = (unsigned short*)alloc((size_t)8 * 1024 * 512 * 2);
  unsigned short* W1t  = (unsigned short*)alloc((size_t)8 * 1024 * 1024 * 2);
  unsigned short* W2t  = (unsigned short*)alloc((size_t)8 * 1024 * 1024 * 2);
  unsigned short* h0   = (unsigned short*)alloc((size_t)B_SZ * NTOT * 2);
  unsigned short* h1   = (unsigned short*)alloc((size_t)B_SZ * NTOT * 2);
  unsigned short* eo   = (unsigned short*)alloc((size_t)B_SZ * NTOT * 2);
  (void)ws_size; (void)in_sizes; (void)n_in; (void)out_size;

  k_obs_bf16<<<(B_SZ * OBS) / 256, 256, 0, stream>>>(x, obsB);
  k_wt64<<<dim3(16, 8, 8),  256, 0, stream>>>(W0, W0t, 512);
  k_wt64<<<dim3(16, 16, 8), 256, 0, stream>>>(W1, W1t, 1024);
  k_wt64<<<dim3(16, 16, 8), 256, 0, stream>>>(W2, W2t, 1024);

  k_gemm256<true ><<<512, 512, 131072, stream>>>(obsB, 512,  0,    W0t, 512,  b0, h0);
  k_gemm256<true ><<<512, 512, 131072, stream>>>(h0,   NTOT, 1024, W1t, 1024, b1, h1);
  k_gemm256<false><<<512, 512, 131072, stream>>>(h1,   NTOT, 1024, W2t, 1024, b2, eo);

  k_gs_wave<<<B_SZ / 4, 256, 0, stream>>>(eo, x, te_W, headW, headb, out);
}

// Round 16
// 233.699 us; speedup vs baseline: 1.1446x; 1.0817x over previous
//
#include <hip/hip_runtime.h>
#include <stdint.h>

#define B_SZ   4096
#define OBS    512
#define T_TASKS 10
#define E_EXP  8
#define W_DIM  1024
#define H_OUT  12
#define XROW   522      // OBS + T
#define NTOT   8192     // E*W

using f32x4  = __attribute__((ext_vector_type(4))) float;
using bf16x8 = __attribute__((ext_vector_type(8))) short;

__device__ __forceinline__ unsigned short f2bf(float f) {
  union { float f; unsigned u; } x; x.f = f;
  unsigned r = x.u + 0x7FFF + ((x.u >> 16) & 1);   // RNE
  return (unsigned short)(r >> 16);
}
__device__ __forceinline__ float bf2f(unsigned short h) {
  union { unsigned u; float f; } x; x.u = ((unsigned)h) << 16;
  return x.f;
}

__device__ __forceinline__ void gload_lds16(const void* g, void* l) {
  __builtin_amdgcn_global_load_lds(
      (const __attribute__((address_space(1))) void*)g,
      (__attribute__((address_space(3))) void*)l,
      16, 0, 0);
}

#define SCHED0  __builtin_amdgcn_sched_barrier(0)
#define VMCNT6  do { asm volatile("s_waitcnt vmcnt(6)" ::: "memory"); SCHED0; } while (0)
#define LGKM0   do { asm volatile("s_waitcnt lgkmcnt(0)" ::: "memory"); SCHED0; } while (0)
#define BARRIER do { SCHED0; asm volatile("s_barrier" ::: "memory"); SCHED0; } while (0)

// ---------------- merged prep kernel ----------------
// grid = 8192 (obs->bf16) + 1024 (W0t) + 2048 (W1t) + 2048 (W2t) = 13312 blocks x 256.
// Transpose part: W [e][K][1024] f32 -> Wt [e][1024][K] bf16, 64x64 tiles,
// float4 loads -> LDS [64][65] -> 16-bf16-packed stores (k_wt64 logic, verified r10-r15).

__global__ __launch_bounds__(256) void k_prep(
    const float* __restrict__ x, unsigned short* __restrict__ obsB,
    const float* __restrict__ W0, unsigned short* __restrict__ W0t,
    const float* __restrict__ W1, unsigned short* __restrict__ W1t,
    const float* __restrict__ W2, unsigned short* __restrict__ W2t)
{
  __shared__ float tile[64][65];
  int bid = blockIdx.x;
  int tid = threadIdx.x;

  if (bid < 8192) {                                // obs -> bf16, exact grid
    int i = bid * 256 + tid;
    int b = i >> 9, c = i & 511;
    obsB[i] = f2bf(x[(size_t)b * XROW + c]);
    return;
  }
  bid -= 8192;
  const float* Ws; unsigned short* Wd; int K;
  if (bid < 1024)            { Ws = W0; Wd = W0t; K = 512;  }
  else if (bid < 1024+2048)  { bid -= 1024; Ws = W1; Wd = W1t; K = 1024; }
  else                       { bid -= 3072; Ws = W2; Wd = W2t; K = 1024; }
  int ny = K >> 6;                                 // k-tiles
  int bx = bid & 15, rem = bid >> 4;
  int by = rem % ny, e = rem / ny;
  int n0 = bx * 64, k0 = by * 64;
  const float* We = Ws + (size_t)e * K * W_DIM;
  unsigned short* Wde = Wd + (size_t)e * W_DIM * K;

  int tx = tid & 15, ty = tid >> 4;                // tx: n-float4 idx, ty: 0..15
#pragma unroll
  for (int r = 0; r < 4; ++r) {
    int k = ty + r * 16;
    float4 v = *(const float4*)&We[(size_t)(k0 + k) * W_DIM + n0 + tx * 4];
    tile[k][tx * 4 + 0] = v.x; tile[k][tx * 4 + 1] = v.y;
    tile[k][tx * 4 + 2] = v.z; tile[k][tx * 4 + 3] = v.w;
  }
  __syncthreads();
  int n = tid >> 2, kc = (tid & 3) * 16;
  bf16x8 o0, o1;
#pragma unroll
  for (int j = 0; j < 8; ++j) o0[j] = (short)f2bf(tile[kc + j][n]);
#pragma unroll
  for (int j = 0; j < 8; ++j) o1[j] = (short)f2bf(tile[kc + 8 + j][n]);
  unsigned short* dst = &Wde[(size_t)(n0 + n) * K + k0 + kc];
  *(bf16x8*)&dst[0] = o0;
  *(bf16x8*)&dst[8] = o1;
}

// ---------------- 256x256 GEMM, m201 stage map: one vmcnt(6) per K-tile (r13) ----------------
// 512 thr = 8 waves (2M x 4N). BK=64, dbuf LDS 128 KB.
// Window frame: { [reads] ; stage 1 half ; [vmcnt] ; BARRIER ; [lgkm0] ; 16 MFMA }
// Reads: Q0 af<-A0(t)[8]+bf0<-B0(t)[4]; Q1 bf1<-B1(t)[4]; Q2 af<-A1(t)[8]; Q3 none.
// Stages: Q0 A1(t+1)->nbuf; Q1 A0(t+2)->buf; Q2 B0(t+2)->buf; Q3 B1(t+2)->buf.
// Single vmcnt(6)@Q3 retires all of tile t+1 (FIFO proof r13). Measured: 71.0-71.6 us,
// MfmaUtil ~41%, 0 bank conflicts — best of 7 structural variants (r3-r15).

template <bool RELU>
__global__ __launch_bounds__(512, 2) void k_gemm256(
    const unsigned short* __restrict__ A, int lda, int aExpStride,
    const unsigned short* __restrict__ Bt, int K,
    const float* __restrict__ bias,
    unsigned short* __restrict__ C)
{
  extern __shared__ char lds[];
  const int tid  = threadIdx.x;
  const int lane = tid & 63, wid = tid >> 6;
  const int wm = wid >> 2, wn = wid & 3;
  const int rlo = lane & 15, kg = lane >> 4;

  // bijective XCD swizzle: 512 blocks -> 8 XCDs x (8 mblk x 8 nblk)
  int bid = blockIdx.x;
  int xcd = bid & 7, loc = bid >> 3;
  int mblk = ((xcd & 1) << 3) | (loc & 7);
  int nblk = ((xcd >> 1) << 3) | (loc >> 3);
  int m0 = mblk * 256, n0g = nblk * 256;
  int e = n0g >> 10, n0e = n0g & 1023;

  const unsigned short* Ab = A + (size_t)e * aExpStride;
  const unsigned short* Bb = Bt + ((size_t)e * 1024 + n0e) * (size_t)K;

  // staging coords: half-tile = 128 rows x 8 chunks(16B) = 1024 chunks; 2/thread
  const int idx0 = tid, idx1 = 512 + tid;
  const int r0 = idx0 >> 3, p0 = idx0 & 7, c0 = p0 ^ (r0 & 7);  // inverse-swz source
  const int r1 = idx1 >> 3, p1 = idx1 & 7, c1 = p1 ^ (r1 & 7);

  const int NT = K >> 6;
  const size_t ldaz = (size_t)lda, ldkz = (size_t)K;

  auto stageA = [&](int buf, int h, int kt) {
    const unsigned short* g0 = Ab + (size_t)(m0 + h * 128 + r0) * ldaz + kt * 64 + c0 * 8;
    const unsigned short* g1 = Ab + (size_t)(m0 + h * 128 + r1) * ldaz + kt * 64 + c1 * 8;
    char* l = lds + buf * 65536 + h * 16384;
    gload_lds16(g0, l + idx0 * 16);
    gload_lds16(g1, l + idx1 * 16);
  };
  auto stageB = [&](int buf, int h, int kt) {
    const unsigned short* g0 = Bb + (size_t)(h * 128 + r0) * ldkz + kt * 64 + c0 * 8;
    const unsigned short* g1 = Bb + (size_t)(h * 128 + r1) * ldkz + kt * 64 + c1 * 8;
    char* l = lds + buf * 65536 + 32768 + h * 16384;
    gload_lds16(g0, l + idx0 * 16);
    gload_lds16(g1, l + idx1 * 16);
  };
  auto rdA = [&](int buf, int mh, int mi, int ks) -> bf16x8 {
    int r = mi * 32 + wm * 16 + rlo;
    int p = (ks * 4 + kg) ^ (r & 7);               // swizzled read
    return *(const bf16x8*)(lds + buf * 65536 + mh * 16384 + r * 128 + p * 16);
  };
  auto rdB = [&](int buf, int nh, int ni, int ks) -> bf16x8 {
    int r = ni * 64 + wn * 16 + rlo;
    int p = (ks * 4 + kg) ^ (r & 7);
    return *(const bf16x8*)(lds + buf * 65536 + 32768 + nh * 16384 + r * 128 + p * 16);
  };

  f32x4 acc[8][4];
#pragma unroll
  for (int i = 0; i < 8; ++i)
#pragma unroll
    for (int j = 0; j < 4; ++j) acc[i][j] = f32x4{0.f, 0.f, 0.f, 0.f};

  bf16x8 af[8], bf0[4], bf1[4];

  // prologue: tile0 fully (A0,B0,B1,A1) + tile1 A0,B0,B1 = 14 loads.
  // vmcnt(6) retires the 8 oldest = all of tile 0 -> barrier -> reads safe.
  {
    int t1 = NT > 1 ? 1 : 0;
    stageA(0, 0, 0); stageB(0, 0, 0); stageB(0, 1, 0); stageA(0, 1, 0);
    stageA(1, 0, t1); stageB(1, 0, t1); stageB(1, 1, t1);
    VMCNT6;
    BARRIER;
  }

  for (int t = 0; t < NT; ++t) {
    int buf = t & 1, nbuf = buf ^ 1;
    int tn  = (t + 1 < NT) ? t + 1 : NT - 1;       // clamped: counts stay exact;
    int tn2 = (t + 2 < NT) ? t + 2 : NT - 1;       // dead data lands in unread slots

    // ---- Q0: reads af<-A0(t)[8], bf0<-B0(t)[4]; stage A1(t+1)->nbuf ----
#pragma unroll
    for (int mi = 0; mi < 4; ++mi)
#pragma unroll
      for (int ks = 0; ks < 2; ++ks) af[mi * 2 + ks] = rdA(buf, 0, mi, ks);
#pragma unroll
    for (int ni = 0; ni < 2; ++ni)
#pragma unroll
      for (int ks = 0; ks < 2; ++ks) bf0[ni * 2 + ks] = rdB(buf, 0, ni, ks);
    stageA(nbuf, 1, tn);
    BARRIER;
    LGKM0;
    __builtin_amdgcn_s_setprio(1);
#pragma unroll
    for (int ks = 0; ks < 2; ++ks)
#pragma unroll
      for (int mi = 0; mi < 4; ++mi)
#pragma unroll
        for (int ni = 0; ni < 2; ++ni)
          acc[mi][ni] = __builtin_amdgcn_mfma_f32_16x16x32_bf16(af[mi * 2 + ks], bf0[ni * 2 + ks], acc[mi][ni], 0, 0, 0);
    __builtin_amdgcn_s_setprio(0);

    // ---- Q1: reads bf1<-B1(t)[4]; stage A0(t+2)->buf ----
#pragma unroll
    for (int ni = 0; ni < 2; ++ni)
#pragma unroll
      for (int ks = 0; ks < 2; ++ks) bf1[ni * 2 + ks] = rdB(buf, 1, ni, ks);
    stageA(buf, 0, tn2);
    BARRIER;
    LGKM0;
    __builtin_amdgcn_s_setprio(1);
#pragma unroll
    for (int ks = 0; ks < 2; ++ks)
#pragma unroll
      for (int mi = 0; mi < 4; ++mi)
#pragma unroll
        for (int ni = 0; ni < 2; ++ni)
          acc[mi][2 + ni] = __builtin_amdgcn_mfma_f32_16x16x32_bf16(af[mi * 2 + ks], bf1[ni * 2 + ks], acc[mi][2 + ni], 0, 0, 0);
    __builtin_amdgcn_s_setprio(0);

    // ---- Q2: reads af<-A1(t)[8]; stage B0(t+2)->buf ----
#pragma unroll
    for (int mi = 0; mi < 4; ++mi)
#pragma unroll
      for (int ks = 0; ks < 2; ++ks) af[mi * 2 + ks] = rdA(buf, 1, mi, ks);
    stageB(buf, 0, tn2);
    BARRIER;
    LGKM0;
    __builtin_amdgcn_s_setprio(1);
#pragma unroll
    for (int ks = 0; ks < 2; ++ks)
#pragma unroll
      for (int mi = 0; mi < 4; ++mi)
#pragma unroll
        for (int ni = 0; ni < 2; ++ni)
          acc[4 + mi][2 + ni] = __builtin_amdgcn_mfma_f32_16x16x32_bf16(af[mi * 2 + ks], bf1[ni * 2 + ks], acc[4 + mi][2 + ni], 0, 0, 0);
    __builtin_amdgcn_s_setprio(0);

    // ---- Q3: stage B1(t+2)->buf; vmcnt(6) retires all of tile t+1; no new reads ----
    stageB(buf, 1, tn2);
    VMCNT6;
    BARRIER;
    __builtin_amdgcn_s_setprio(1);
#pragma unroll
    for (int ks = 0; ks < 2; ++ks)
#pragma unroll
      for (int mi = 0; mi < 4; ++mi)
#pragma unroll
        for (int ni = 0; ni < 2; ++ni)
          acc[4 + mi][ni] = __builtin_amdgcn_mfma_f32_16x16x32_bf16(af[mi * 2 + ks], bf0[ni * 2 + ks], acc[4 + mi][ni], 0, 0, 0);
    __builtin_amdgcn_s_setprio(0);
  }
  asm volatile("s_waitcnt vmcnt(0)" ::: "memory");
  SCHED0;

  // epilogue: bias (+ReLU) + bf16 store
  int rbase = kg * 4;
#pragma unroll
  for (int fi = 0; fi < 8; ++fi) {
    int mh = fi >> 2, mi = fi & 3;
    int rowg = m0 + mh * 128 + mi * 32 + wm * 16 + rbase;
#pragma unroll
    for (int fj = 0; fj < 4; ++fj) {
      int nh = fj >> 1, ni = fj & 1;
      int colr = nh * 128 + ni * 64 + wn * 16 + rlo;
      int colg = n0g + colr;
      float bv = bias[e * W_DIM + n0e + colr];
#pragma unroll
      for (int j = 0; j < 4; ++j) {
        float v = acc[fi][fj][j] + bv;
        if (RELU) v = fmaxf(v, 0.0f);
        C[(size_t)(rowg + j) * NTOT + colg] = f2bf(v);
      }
    }
  }
}

// ---------------- Gram-Schmidt + feat + head: one WAVE per batch row ----------------
// Tree-reduced (4 partial accumulators) dot products: cuts the 16-deep serial FMA
// chain on the GS critical path (36 reductions/row, only 4 waves/SIMD to hide it).

__device__ __forceinline__ float wred(float s) {
#pragma unroll
  for (int m = 32; m; m >>= 1) s += __shfl_xor(s, m, 64);
  return s;
}

__global__ __launch_bounds__(256, 1) void k_gs_wave(
    const unsigned short* __restrict__ eo,   // [B][8192] bf16
    const float* __restrict__ x,
    const float* __restrict__ te_W,          // [10][8]
    const float* __restrict__ head_W,        // [10][1024][12]
    const float* __restrict__ head_b,        // [10][12]
    float* __restrict__ out)                 // [B][12]
{
  int wid = threadIdx.x >> 6, lane = threadIdx.x & 63;
  int b = blockIdx.x * 4 + wid;

  float v[8][16];
  const unsigned short* row = eo + (size_t)b * NTOT;
#pragma unroll
  for (int i = 0; i < E_EXP; ++i) {
#pragma unroll
    for (int half = 0; half < 2; ++half) {
      bf16x8 t = *(const bf16x8*)&row[i * 1024 + half * 512 + lane * 8];
#pragma unroll
      for (int k = 0; k < 8; ++k) v[i][half * 8 + k] = bf2f((unsigned short)t[k]);
    }
  }

  int idx = 0; float mv = x[(size_t)b * XROW + OBS];
#pragma unroll
  for (int t = 1; t < T_TASKS; ++t) {
    float val = x[(size_t)b * XROW + OBS + t];
    if (val > mv) { mv = val; idx = t; }
  }

  float cf[7];
#pragma unroll
  for (int i = 0; i < E_EXP; ++i) {
#pragma unroll
    for (int j = 0; j < 7; ++j) {
      if (j < i) {
        float q0 = 0.f, q1 = 0.f, q2 = 0.f, q3 = 0.f;
#pragma unroll
        for (int c = 0; c < 16; c += 4) {
          q0 += v[i][c + 0] * v[j][c + 0];
          q1 += v[i][c + 1] * v[j][c + 1];
          q2 += v[i][c + 2] * v[j][c + 2];
          q3 += v[i][c + 3] * v[j][c + 3];
        }
        cf[j] = wred((q0 + q1) + (q2 + q3));
      }
    }
#pragma unroll
    for (int c = 0; c < 16; ++c) {
      float w = v[i][c];
#pragma unroll
      for (int j = 0; j < 7; ++j)
        if (j < i) w -= cf[j] * v[j][c];
      v[i][c] = w;
    }
    float q0 = 0.f, q1 = 0.f, q2 = 0.f, q3 = 0.f;
#pragma unroll
    for (int c = 0; c < 16; c += 4) {
      q0 += v[i][c + 0] * v[i][c + 0];
      q1 += v[i][c + 1] * v[i][c + 1];
      q2 += v[i][c + 2] * v[i][c + 2];
      q3 += v[i][c + 3] * v[i][c + 3];
    }
    float nrm = sqrtf(wred((q0 + q1) + (q2 + q3)));
    float s = 1.0f / (nrm + 1e-8f);
#pragma unroll
    for (int c = 0; c < 16; ++c) v[i][c] *= s;
  }

  float te[E_EXP];
#pragma unroll
  for (int e2 = 0; e2 < E_EXP; ++e2) te[e2] = te_W[idx * E_EXP + e2];

  float ph[H_OUT];
#pragma unroll
  for (int h = 0; h < H_OUT; ++h) ph[h] = 0.f;
  const float* hw = head_W + (size_t)idx * W_DIM * H_OUT;

#pragma unroll
  for (int half = 0; half < 2; ++half) {
#pragma unroll
    for (int k = 0; k < 8; ++k) {
      int c = half * 512 + lane * 8 + k;
      float f = 0.f;
#pragma unroll
      for (int e2 = 0; e2 < E_EXP; ++e2) f += te[e2] * v[e2][half * 8 + k];
      // fast tanh: 1 - 2/(e^{2f}+1) via v_exp_f32
      float ex = __expf(2.0f * f);
      f = 1.0f - 2.0f / (ex + 1.0f);
      const float4* hw4 = (const float4*)(hw + (size_t)c * H_OUT);
      float4 h0 = hw4[0], h1 = hw4[1], h2 = hw4[2];
      ph[0] += f * h0.x;  ph[1] += f * h0.y;  ph[2]  += f * h0.z;  ph[3]  += f * h0.w;
      ph[4] += f * h1.x;  ph[5] += f * h1.y;  ph[6]  += f * h1.z;  ph[7]  += f * h1.w;
      ph[8] += f * h2.x;  ph[9] += f * h2.y;  ph[10] += f * h2.z;  ph[11] += f * h2.w;
    }
  }

#pragma unroll
  for (int h = 0; h < H_OUT; ++h) ph[h] = wred(ph[h]);
  if (lane == 0) {
#pragma unroll
    for (int h = 0; h < H_OUT; ++h)
      out[(size_t)b * H_OUT + h] = ph[h] + head_b[idx * H_OUT + h];
  }
}

// ---------------- launch ----------------

extern "C" void kernel_launch(void* const* d_in, const int* in_sizes, int n_in,
                              void* d_out, int out_size, void* d_ws, size_t ws_size,
                              hipStream_t stream) {
  const float* x     = (const float*)d_in[0];
  const float* te_W  = (const float*)d_in[1];
  const float* W0    = (const float*)d_in[2];
  const float* b0    = (const float*)d_in[3];
  const float* W1    = (const float*)d_in[4];
  const float* b1    = (const float*)d_in[5];
  const float* W2    = (const float*)d_in[6];
  const float* b2    = (const float*)d_in[7];
  const float* headW = (const float*)d_in[8];
  const float* headb = (const float*)d_in[9];
  float* out = (float*)d_out;

  char* ws = (char*)d_ws;
  size_t off = 0;
  auto alloc = [&](size_t bytes) {
    void* p = ws + off;
    off += (bytes + 255) & ~(size_t)255;
    return p;
  };
  unsigned short* obsB = (unsigned short*)alloc((size_t)B_SZ * OBS * 2);
  unsigned short* W0t  = (unsigned short*)alloc((size_t)8 * 1024 * 512 * 2);
  unsigned short* W1t  = (unsigned short*)alloc((size_t)8 * 1024 * 1024 * 2);
  unsigned short* W2t  = (unsigned short*)alloc((size_t)8 * 1024 * 1024 * 2);
  unsigned short* h0   = (unsigned short*)alloc((size_t)B_SZ * NTOT * 2);
  unsigned short* h1   = (unsigned short*)alloc((size_t)B_SZ * NTOT * 2);
  unsigned short* eo   = (unsigned short*)alloc((size_t)B_SZ * NTOT * 2);
  (void)ws_size; (void)in_sizes; (void)n_in; (void)out_size;

  // merged prep: 8192 (obs) + 1024 (W0t) + 2048 (W1t) + 2048 (W2t)
  k_prep<<<13312, 256, 0, stream>>>(x, obsB, W0, W0t, W1, W1t, W2, W2t);

  k_gemm256<true ><<<512, 512, 131072, stream>>>(obsB, 512,  0,    W0t, 512,  b0, h0);
  k_gemm256<true ><<<512, 512, 131072, stream>>>(h0,   NTOT, 1024, W1t, 1024, b1, h1);
  k_gemm256<false><<<512, 512, 131072, stream>>>(h1,   NTOT, 1024, W2t, 1024, b2, eo);

  k_gs_wave<<<B_SZ / 4, 256, 0, stream>>>(eo, x, te_W, headW, headb, out);
}